// Round 1
// 680.803 us; speedup vs baseline: 1.0024x; 1.0024x over previous
//
#include <hip/hip_runtime.h>
#include <hip/hip_bf16.h>

#define NB 2048
#define NL 128
#define ND 512

__device__ __forceinline__ float bf2f(unsigned int u) {
    union { unsigned int i; float f; } x;
    x.i = u << 16;
    return x.f;
}

// One block per batch element b. 256 threads = 4 waves, 8 blocks/CU resident.
// Phase 1: compute new_a_t[b, :] (length 128) in LDS, write (f32) to d_out tail.
// Phase 2: output[b, d] = sum_l new_a[l] * ie[b, l, d]; each wave covers 32
// contiguous rows via a depth-2 register-rotation pipeline (row i+2 issued
// before row i's FMAs -> loads stay in flight, no vmcnt(0) drain per group).
// OUTPUT IS ALWAYS float32. Input dtype probed via a_t row-sum == 1 check.
// __launch_bounds__(256, 8): 8 blocks/CU = 32 waves/CU, VGPR cap 64 — the
// pipeline is sized (~45 VGPR) to fit without spill.
__global__ __launch_bounds__(256, 8) void sa_kernel(
    const void* __restrict__ a_t_v,
    const void* __restrict__ r_t_v,
    const void* __restrict__ ie_v,
    const void* __restrict__ mask_v,
    float* __restrict__ out)
{
    const int b = blockIdx.x;
    const int tid = threadIdx.x;

    __shared__ float aS[NL], mS[NL], wsS[NL], naS[NL];
    __shared__ float partial[4][ND];
    __shared__ int flagS;
    __shared__ float r01S[2];

    // --- input dtype probe (first 256 B of a_t — in-bounds either way) ---
    if (tid < 64) {
        const unsigned short* hus = (const unsigned short*)a_t_v;
        float sbf = bf2f(hus[2 * tid]) + bf2f(hus[2 * tid + 1]);
        #pragma unroll
        for (int off = 32; off; off >>= 1) sbf += __shfl_down(sbf, off);
        if (tid == 0) flagS = (fabsf(sbf - 1.0f) < 0.05f) ? 1 : 0;
    }
    __syncthreads();
    const int isbf = flagS;

    // --- load row b of a_t, mask, r_t under the detected dtype ---
    if (isbf) {
        if (tid < NL) {
            const unsigned short* aus = (const unsigned short*)a_t_v + (size_t)b * NL;
            const unsigned short* mus = (const unsigned short*)mask_v + (size_t)b * NL;
            aS[tid] = bf2f(aus[tid]); mS[tid] = bf2f(mus[tid]);
        }
        if (tid == 0) {
            const unsigned short* rus = (const unsigned short*)r_t_v + (size_t)b * 2;
            r01S[0] = bf2f(rus[0]); r01S[1] = bf2f(rus[1]);
        }
    } else {
        if (tid < NL) {
            const float* af = (const float*)a_t_v + (size_t)b * NL;
            const float* mf = (const float*)mask_v + (size_t)b * NL;
            aS[tid] = af[tid]; mS[tid] = mf[tid];
        }
        if (tid == 0) {
            const float* rf = (const float*)r_t_v + (size_t)b * 2;
            r01S[0] = rf[0]; r01S[1] = rf[1];
        }
    }
    __syncthreads();
    const float r0 = r01S[0], r1 = r01S[1];

    // ws[i] = a[i]*r1 + a[i+1]*r0, i in [0,126]
    if (tid < NL - 1) wsS[tid] = aS[tid] * r1 + aS[tid + 1] * r0;
    __syncthreads();

    // new_a[l] = (l==0 ? a0*r0 : mask[l]*ws[l-1]) + (l<127 ? (1-mask[l+1])*ws[l] : 0)
    if (tid < NL) {
        float v = (tid == 0) ? aS[0] * r0 : mS[tid] * wsS[tid - 1];
        if (tid < NL - 1) v += (1.0f - mS[tid + 1]) * wsS[tid];
        naS[tid] = v;
        out[(size_t)NB * ND + (size_t)b * NL + tid] = v;   // f32 tail: new_a_t
    }
    __syncthreads();

    // --- phase 2: weighted row-sum over input_embedding[b] ---
    const int w = tid >> 6;   // wave id 0..3 -> rows [w*32, w*32+32)
    const int c = tid & 63;   // lane
    const float* naP = &naS[w * 32];

    float acc[8];
    #pragma unroll
    for (int j = 0; j < 8; ++j) acc[j] = 0.f;

    if (isbf) {
        // lane c owns d in [c*8, c*8+8): one 16 B load per row (row = 1 KiB).
        // depth-2 rotation: cu=row i, nx=row i+1, t=row i+2 issued pre-FMA.
        const uint4* p = (const uint4*)((const unsigned short*)ie_v + (size_t)b * NL * ND)
                         + (size_t)(w * 32) * (ND / 8);
        uint4 cu = p[c];
        uint4 nx = p[64 + c];
        #pragma unroll 2
        for (int i = 0; i < 30; ++i) {
            uint4 t = p[(i + 2) * 64 + c];
            const float na = naP[i];
            acc[0] = fmaf(na, bf2f(cu.x & 0xffffu), acc[0]);
            acc[1] = fmaf(na, bf2f(cu.x >> 16),     acc[1]);
            acc[2] = fmaf(na, bf2f(cu.y & 0xffffu), acc[2]);
            acc[3] = fmaf(na, bf2f(cu.y >> 16),     acc[3]);
            acc[4] = fmaf(na, bf2f(cu.z & 0xffffu), acc[4]);
            acc[5] = fmaf(na, bf2f(cu.z >> 16),     acc[5]);
            acc[6] = fmaf(na, bf2f(cu.w & 0xffffu), acc[6]);
            acc[7] = fmaf(na, bf2f(cu.w >> 16),     acc[7]);
            cu = nx; nx = t;
        }
        {   // row 30
            const float na = naP[30];
            acc[0] = fmaf(na, bf2f(cu.x & 0xffffu), acc[0]);
            acc[1] = fmaf(na, bf2f(cu.x >> 16),     acc[1]);
            acc[2] = fmaf(na, bf2f(cu.y & 0xffffu), acc[2]);
            acc[3] = fmaf(na, bf2f(cu.y >> 16),     acc[3]);
            acc[4] = fmaf(na, bf2f(cu.z & 0xffffu), acc[4]);
            acc[5] = fmaf(na, bf2f(cu.z >> 16),     acc[5]);
            acc[6] = fmaf(na, bf2f(cu.w & 0xffffu), acc[6]);
            acc[7] = fmaf(na, bf2f(cu.w >> 16),     acc[7]);
        }
        {   // row 31
            const float na = naP[31];
            acc[0] = fmaf(na, bf2f(nx.x & 0xffffu), acc[0]);
            acc[1] = fmaf(na, bf2f(nx.x >> 16),     acc[1]);
            acc[2] = fmaf(na, bf2f(nx.y & 0xffffu), acc[2]);
            acc[3] = fmaf(na, bf2f(nx.y >> 16),     acc[3]);
            acc[4] = fmaf(na, bf2f(nx.z & 0xffffu), acc[4]);
            acc[5] = fmaf(na, bf2f(nx.z >> 16),     acc[5]);
            acc[6] = fmaf(na, bf2f(nx.w & 0xffffu), acc[6]);
            acc[7] = fmaf(na, bf2f(nx.w >> 16),     acc[7]);
        }
        #pragma unroll
        for (int j = 0; j < 8; ++j) partial[w][c * 8 + j] = acc[j];
    } else {
        // acc[0..3] -> d = 4c+j, acc[4..7] -> d = 1024B-offset half; both float4
        // streams wave-contiguous. depth-2 rotation as above (16 data VGPRs).
        const float4* p = (const float4*)((const float*)ie_v + (size_t)b * NL * ND)
                          + (size_t)(w * 32) * (ND / 4);
        float4 c0 = p[c],       c1 = p[64 + c];
        float4 n0 = p[128 + c], n1 = p[128 + 64 + c];
        #pragma unroll 2
        for (int i = 0; i < 30; ++i) {
            float4 t0 = p[(i + 2) * 128 + c];
            float4 t1 = p[(i + 2) * 128 + 64 + c];
            const float na = naP[i];
            acc[0] = fmaf(na, c0.x, acc[0]);
            acc[1] = fmaf(na, c0.y, acc[1]);
            acc[2] = fmaf(na, c0.z, acc[2]);
            acc[3] = fmaf(na, c0.w, acc[3]);
            acc[4] = fmaf(na, c1.x, acc[4]);
            acc[5] = fmaf(na, c1.y, acc[5]);
            acc[6] = fmaf(na, c1.z, acc[6]);
            acc[7] = fmaf(na, c1.w, acc[7]);
            c0 = n0; c1 = n1; n0 = t0; n1 = t1;
        }
        {   // row 30
            const float na = naP[30];
            acc[0] = fmaf(na, c0.x, acc[0]);
            acc[1] = fmaf(na, c0.y, acc[1]);
            acc[2] = fmaf(na, c0.z, acc[2]);
            acc[3] = fmaf(na, c0.w, acc[3]);
            acc[4] = fmaf(na, c1.x, acc[4]);
            acc[5] = fmaf(na, c1.y, acc[5]);
            acc[6] = fmaf(na, c1.z, acc[6]);
            acc[7] = fmaf(na, c1.w, acc[7]);
        }
        {   // row 31
            const float na = naP[31];
            acc[0] = fmaf(na, n0.x, acc[0]);
            acc[1] = fmaf(na, n0.y, acc[1]);
            acc[2] = fmaf(na, n0.z, acc[2]);
            acc[3] = fmaf(na, n0.w, acc[3]);
            acc[4] = fmaf(na, n1.x, acc[4]);
            acc[5] = fmaf(na, n1.y, acc[5]);
            acc[6] = fmaf(na, n1.z, acc[6]);
            acc[7] = fmaf(na, n1.w, acc[7]);
        }
        #pragma unroll
        for (int j = 0; j < 4; ++j) partial[w][4 * c + j] = acc[j];
        #pragma unroll
        for (int j = 0; j < 4; ++j) partial[w][256 + 4 * c + j] = acc[4 + j];
    }
    __syncthreads();

    #pragma unroll
    for (int k = 0; k < 2; ++k) {
        const int d = tid + k * 256;
        float s = partial[0][d] + partial[1][d] + partial[2][d] + partial[3][d];
        out[(size_t)b * ND + d] = s;   // f32 main output
    }
}

extern "C" void kernel_launch(void* const* d_in, const int* in_sizes, int n_in,
                              void* d_out, int out_size, void* d_ws, size_t ws_size,
                              hipStream_t stream) {
    (void)in_sizes; (void)n_in; (void)out_size; (void)d_ws; (void)ws_size;
    const void* a_t  = d_in[0];
    const void* r_t  = d_in[1];
    const void* ie   = d_in[2];
    const void* mask = d_in[3];
    // d_in[4] is `step` (unused by the math).
    sa_kernel<<<dim3(NB), dim3(256), 0, stream>>>(a_t, r_t, ie, mask, (float*)d_out);
}

// Round 2
// 674.279 us; speedup vs baseline: 1.0121x; 1.0097x over previous
//
#include <hip/hip_runtime.h>
#include <hip/hip_bf16.h>

#define NB 2048
#define NL 128
#define ND 512
#define BPB 4            // batches per block
#define NBLK (NB / BPB)  // 512 blocks

__device__ __forceinline__ float bf2f(unsigned int u) {
    union { unsigned int i; float f; } x;
    x.i = u << 16;
    return x.f;
}

// 512 blocks x 512 threads (8 waves, 2 blocks/CU); each block owns 4
// CONSECUTIVE batches (4 x 128 KB bf16 contiguous slab).
// Phase 0: new_a_t for all 4 batches computed in one parallel LDS pass.
// Phase 2 per batch: wave w owns rows {w, 8+w, ..., 120+w} so the 8 waves
// cover 8 CONSECUTIVE rows at each step; each wave issues all 16 row-loads
// (dwordx4 = 1 KB bf16 row) back-to-back -> the whole 128 KB slab is in
// flight as one dense address burst. This replaces 8192 power-of-2-spaced
// lockstep streams (DRAM row/channel thrash at ~12% efficiency) with 512
// dense sequential streams. 8-wave LDS reduce, f32 store.
// OUTPUT IS ALWAYS float32. Input dtype probed via a_t row-sum == 1 check.
__global__ __launch_bounds__(512, 4) void sa_kernel(
    const void* __restrict__ a_t_v,
    const void* __restrict__ r_t_v,
    const void* __restrict__ ie_v,
    const void* __restrict__ mask_v,
    float* __restrict__ out)
{
    const int tid = threadIdx.x;
    const int w = tid >> 6;     // wave 0..7
    const int c = tid & 63;     // lane
    const int b0 = blockIdx.x * BPB;

    __shared__ float aA[BPB][NL], mA[BPB][NL], wsA[BPB][NL], naA[BPB][NL];
    __shared__ __align__(16) float partial[8][ND];
    __shared__ float rA[BPB][2];
    __shared__ int flagS;

    // --- dtype probe (first 256 B of a_t; row 0 sums to ~1 iff bf16) ---
    if (tid < 64) {
        const unsigned short* hus = (const unsigned short*)a_t_v;
        float sbf = bf2f(hus[2 * tid]) + bf2f(hus[2 * tid + 1]);
        #pragma unroll
        for (int off = 32; off; off >>= 1) sbf += __shfl_down(sbf, off);
        if (tid == 0) flagS = (fabsf(sbf - 1.0f) < 0.05f) ? 1 : 0;
    }
    __syncthreads();
    const int isbf = flagS;

    // --- phase 0: a, mask, r for the block's 4 batches (one coalesced pass;
    //     tid -> (bb = tid>>7, l = tid&127) covers exactly 4*128 elements) ---
    const int bb = tid >> 7;
    const int l  = tid & (NL - 1);
    if (isbf) {
        const unsigned short* aus = (const unsigned short*)a_t_v  + (size_t)b0 * NL;
        const unsigned short* mus = (const unsigned short*)mask_v + (size_t)b0 * NL;
        aA[bb][l] = bf2f(aus[tid]);
        mA[bb][l] = bf2f(mus[tid]);
        if (tid < 2 * BPB) {
            const unsigned short* rus = (const unsigned short*)r_t_v + (size_t)b0 * 2;
            rA[tid >> 1][tid & 1] = bf2f(rus[tid]);
        }
    } else {
        const float* af = (const float*)a_t_v  + (size_t)b0 * NL;
        const float* mf = (const float*)mask_v + (size_t)b0 * NL;
        aA[bb][l] = af[tid];
        mA[bb][l] = mf[tid];
        if (tid < 2 * BPB) {
            const float* rf = (const float*)r_t_v + (size_t)b0 * 2;
            rA[tid >> 1][tid & 1] = rf[tid];
        }
    }
    __syncthreads();

    // ws[i] = a[i]*r1 + a[i+1]*r0, i in [0,126]
    if (l < NL - 1) wsA[bb][l] = aA[bb][l] * rA[bb][1] + aA[bb][l + 1] * rA[bb][0];
    __syncthreads();

    // new_a[l] = (l==0 ? a0*r0 : mask[l]*ws[l-1]) + (l<127 ? (1-mask[l+1])*ws[l] : 0)
    {
        float v = (l == 0) ? aA[bb][0] * rA[bb][0] : mA[bb][l] * wsA[bb][l - 1];
        if (l < NL - 1) v += (1.0f - mA[bb][l + 1]) * wsA[bb][l];
        naA[bb][l] = v;
        out[(size_t)NB * ND + (size_t)b0 * NL + tid] = v;   // f32 tail: new_a_t
    }
    __syncthreads();

    // --- phase 2: weighted row-sum, one dense 128 KB burst per batch ---
    for (int b2 = 0; b2 < BPB; ++b2) {
        const int batch = b0 + b2;
        const float* naB = naA[b2];
        float acc0 = 0.f, acc1 = 0.f, acc2 = 0.f, acc3 = 0.f;
        float acc4 = 0.f, acc5 = 0.f, acc6 = 0.f, acc7 = 0.f;

        if (isbf) {
            // lane c owns d in [8c, 8c+8); row l = k*8 + w; 1 load per row.
            const uint4* p = (const uint4*)((const unsigned short*)ie_v
                             + (size_t)batch * NL * ND) + c;
            uint4 q[16];
            #pragma unroll
            for (int k = 0; k < 16; ++k) q[k] = p[(size_t)(k * 8 + w) * (ND / 8)];
            #pragma unroll
            for (int k = 0; k < 16; ++k) {
                const float na = naB[k * 8 + w];
                acc0 = fmaf(na, bf2f(q[k].x & 0xffffu), acc0);
                acc1 = fmaf(na, bf2f(q[k].x >> 16),     acc1);
                acc2 = fmaf(na, bf2f(q[k].y & 0xffffu), acc2);
                acc3 = fmaf(na, bf2f(q[k].y >> 16),     acc3);
                acc4 = fmaf(na, bf2f(q[k].z & 0xffffu), acc4);
                acc5 = fmaf(na, bf2f(q[k].z >> 16),     acc5);
                acc6 = fmaf(na, bf2f(q[k].w & 0xffffu), acc6);
                acc7 = fmaf(na, bf2f(q[k].w >> 16),     acc7);
            }
            *(float4*)&partial[w][c * 8]     = make_float4(acc0, acc1, acc2, acc3);
            *(float4*)&partial[w][c * 8 + 4] = make_float4(acc4, acc5, acc6, acc7);
        } else {
            // f32 row = 2 KB = 2 wave-loads; acc0..3 -> d=4c+j, acc4..7 -> d=256+4c+j
            const float4* pf = (const float4*)((const float*)ie_v
                               + (size_t)batch * NL * ND) + c;
            float4 f[16];
            #pragma unroll
            for (int k = 0; k < 16; ++k) f[k] = pf[(size_t)(k * 8 + w) * (ND / 4)];
            #pragma unroll
            for (int k = 0; k < 16; ++k) {
                const float na = naB[k * 8 + w];
                acc0 = fmaf(na, f[k].x, acc0);
                acc1 = fmaf(na, f[k].y, acc1);
                acc2 = fmaf(na, f[k].z, acc2);
                acc3 = fmaf(na, f[k].w, acc3);
            }
            #pragma unroll
            for (int k = 0; k < 16; ++k) f[k] = pf[(size_t)(k * 8 + w) * (ND / 4) + 64];
            #pragma unroll
            for (int k = 0; k < 16; ++k) {
                const float na = naB[k * 8 + w];
                acc4 = fmaf(na, f[k].x, acc4);
                acc5 = fmaf(na, f[k].y, acc5);
                acc6 = fmaf(na, f[k].z, acc6);
                acc7 = fmaf(na, f[k].w, acc7);
            }
            *(float4*)&partial[w][c * 4]       = make_float4(acc0, acc1, acc2, acc3);
            *(float4*)&partial[w][256 + c * 4] = make_float4(acc4, acc5, acc6, acc7);
        }
        __syncthreads();
        {
            // 512 threads <-> 512 d; stride-512 between waves' rows -> conflict-free
            float s = partial[0][tid] + partial[1][tid] + partial[2][tid] + partial[3][tid]
                    + partial[4][tid] + partial[5][tid] + partial[6][tid] + partial[7][tid];
            out[(size_t)batch * ND + tid] = s;   // f32 main output
        }
        __syncthreads();   // partial reused by next batch
    }
}

extern "C" void kernel_launch(void* const* d_in, const int* in_sizes, int n_in,
                              void* d_out, int out_size, void* d_ws, size_t ws_size,
                              hipStream_t stream) {
    (void)in_sizes; (void)n_in; (void)out_size; (void)d_ws; (void)ws_size;
    const void* a_t  = d_in[0];
    const void* r_t  = d_in[1];
    const void* ie   = d_in[2];
    const void* mask = d_in[3];
    // d_in[4] is `step` (unused by the math).
    sa_kernel<<<dim3(NBLK), dim3(512), 0, stream>>>(a_t, r_t, ie, mask, (float*)d_out);
}